// Round 12
// baseline (3435.143 us; speedup 1.0000x reference)
//
#include <hip/hip_runtime.h>

#define DM 192      // D_MODEL
#define DI 384      // D_INNER
#define DSt 16      // D_STATE
#define DTR 12      // DT_RANK
#define DC 4        // D_CONV
#define NL 24       // DEPTH
#define HP 14
#define NH 3
#define NB 4        // BATCH
#define SL 197      // seq len (tokens + cls)
#define NT 196      // spatial tokens
#define XZW 768     // 2*D_INNER
#define DBLW 44     // DT_RANK + 2*D_STATE
#define SEG 50      // scan segment length (4 segments: 50,50,50,47)

static __device__ __forceinline__ float siluf(float x) { return x / (1.f + expf(-x)); }
static __device__ __forceinline__ float softplusf(float x) { return (x > 20.f) ? x : log1pf(expf(x)); }

// DPP-based add of a shifted copy (VALU pipe, no LDS crossbar).
template <int CTRL>
static __device__ __forceinline__ float dpp_addf(float x) {
  int y = __builtin_amdgcn_update_dpp(0, __float_as_int(x), CTRL, 0xF, 0xF, true);
  return x + __int_as_float(y);
}

// ---- block reduce helpers ----
static __device__ __forceinline__ float blk_sum3(float v, float* wsum) {
  for (int off = 32; off; off >>= 1) v += __shfl_xor(v, off, 64);
  int wid = threadIdx.x >> 6;
  if ((threadIdx.x & 63) == 0) wsum[wid] = v;
  __syncthreads();
  return wsum[0] + wsum[1] + wsum[2];
}
static __device__ __forceinline__ float blk_sum4(float v, float* wsum) {
  for (int off = 32; off; off >>= 1) v += __shfl_xor(v, off, 64);
  int wid = threadIdx.x >> 6;
  if ((threadIdx.x & 63) == 0) wsum[wid] = v;
  __syncthreads();
  return wsum[0] + wsum[1] + wsum[2] + wsum[3];
}

// ---- rope tables: cos/sin (196,192) ----
__global__ void k_rope_init(float* __restrict__ cosT, float* __restrict__ sinT) {
  int gid = blockIdx.x * blockDim.x + threadIdx.x;
  if (gid >= NT * DM) return;
  int c = gid % DM, tk = gid / DM;
  int py = tk / HP, px = tk % HP;
  int pos = (c < 96) ? py : px;
  int i = (c < 96) ? (c >> 1) : ((c - 96) >> 1);
  double fb = pow(10000.0, -((double)(2 * i)) / 96.0);
  double ang = (double)pos * fb;
  cosT[gid] = (float)cos(ang);
  sinT[gid] = (float)sin(ang);
}

// ---- im2col: P (2, 784, 768) patch matrix ----
__global__ void k_im2col(const float* __restrict__ x1, const float* __restrict__ x2,
                         float* __restrict__ P) {
  int gid = blockIdx.x * blockDim.x + threadIdx.x;
  if (gid >= 2 * 784 * 768) return;
  int col = gid % 768;
  int row = (gid / 768) % 784;
  int e = gid / (768 * 784);
  int b = row / NT, tk = row % NT;
  int c = col >> 8, r = (col >> 4) & 15, xx = col & 15;
  int py = tk / HP, px = tk % HP;
  const float* img = e ? x2 : x1;
  P[gid] = img[((size_t)(b * 3 + c) * 224 + (py * 16 + r)) * 224 + (px * 16 + xx)];
}

// ---- patch epilogue: h = mm_out + pb + pos (cls row special); res = 0 ----
__global__ void k_patch_fin(const float* __restrict__ pm, const float* __restrict__ pb,
                            const float* __restrict__ cls, const float* __restrict__ pos,
                            float* __restrict__ h, float* __restrict__ res) {
  int gid = blockIdx.x * blockDim.x + threadIdx.x;
  if (gid >= 2 * NB * SL * DM) return;
  int c = gid % DM;
  int t = (gid / DM) % SL;
  int b = (gid / (DM * SL)) % NB;
  int e = gid / (DM * SL * NB);
  float v;
  if (t == 0) v = cls[e * DM + c];
  else v = pm[((size_t)e * 784 + b * NT + (t - 1)) * DM + c] + pb[e * DM + c];
  h[gid] = v + pos[((size_t)e * SL + t) * DM + c];
  res[gid] = 0.f;
}

// ---- per layer: rope(h); res += ; hs = rmsnorm(res)*nw ----
__global__ __launch_bounds__(DM) void k_rope_res_norm(
    const float* __restrict__ h, float* __restrict__ res, float* __restrict__ hs,
    const float* __restrict__ nw, const float* __restrict__ cosT,
    const float* __restrict__ sinT, int l) {
  int bx = blockIdx.x;
  int t = bx % SL; int b = (bx / SL) % NB; int e = bx / (SL * NB);
  int c = threadIdx.x;
  __shared__ float sh[DM];
  __shared__ float wsum[3];
  size_t base = ((size_t)(e * NB + b) * SL + t) * DM;
  sh[c] = h[base + c];
  __syncthreads();
  float v = sh[c];
  if (t > 0) {
    int tk = t - 1;
    float co = cosT[tk * DM + c], si = sinT[tk * DM + c];
    float partner = sh[c ^ 1];
    float rot = (c & 1) ? partner : -partner;
    v = v * co + rot * si;
  }
  float r = res[base + c] + v;
  res[base + c] = r;
  float tot = blk_sum3(r * r, wsum);
  float scale = rsqrtf(tot / (float)DM + 1e-5f);
  hs[base + c] = r * scale * nw[(size_t)(e * NL + l) * DM + c];
}

// ---- register-blocked tiled GEMM: C = alpha*(A0[+A1]) @ B^T ----
// 32x64 tile, BK=16, 256 threads, 2x4 outputs/thread (float2 x float4).
struct MM4 {
  const float* A0[4];
  const float* A1[4];
  const float* B[4];
  float* C[4];
};
__global__ __launch_bounds__(256) void k_mm32(MM4 p, int M, int N, int K, float alpha) {
  const float* __restrict__ A0 = p.A0[blockIdx.z];
  const float* __restrict__ A1 = p.A1[blockIdx.z];
  const float* __restrict__ Bw = p.B[blockIdx.z];
  float* __restrict__ C = p.C[blockIdx.z];
  __shared__ __align__(16) float As[16][34];
  __shared__ __align__(16) float Bs[16][68];
  int tid = threadIdx.x;
  int m0 = blockIdx.y * 32, n0 = blockIdx.x * 64;
  int tm = tid >> 4, tn = tid & 15;        // compute roles: rows tm*2..+1, cols tn*4..+3
  int srow = tid >> 2, skq = tid & 3;      // B staging: 64 rows x 4 quads
  int srowA = (tid & 127) >> 2;            // A staging (tid<128): 32 rows x 4 quads
  bool doA = tid < 128;
  int gmA = min(m0 + srowA, M - 1);
  int gnB = min(n0 + srow, N - 1);
  bool hasA1 = (A1 != nullptr);
  float4 ra, rb, ra1;

  auto GLOAD = [&](int k0) {
    if (doA) {
      ra = *(const float4*)&A0[(size_t)gmA * K + k0 + skq * 4];
      if (hasA1) ra1 = *(const float4*)&A1[(size_t)gmA * K + k0 + skq * 4];
    }
    rb = *(const float4*)&Bw[(size_t)gnB * K + k0 + skq * 4];
  };
  auto DSW = [&]() {
    int kb = skq * 4;
    if (doA) {
      float av0 = ra.x, av1 = ra.y, av2 = ra.z, av3 = ra.w;
      if (hasA1) { av0 += ra1.x; av1 += ra1.y; av2 += ra1.z; av3 += ra1.w; }
      As[kb + 0][srowA] = av0;
      As[kb + 1][srowA] = av1;
      As[kb + 2][srowA] = av2;
      As[kb + 3][srowA] = av3;
    }
    Bs[kb + 0][srow] = rb.x;
    Bs[kb + 1][srow] = rb.y;
    Bs[kb + 2][srow] = rb.z;
    Bs[kb + 3][srow] = rb.w;
  };

  float acc[2][4] = {};
  int T = K >> 4;
  GLOAD(0);
  DSW();
  __syncthreads();
#pragma unroll 1
  for (int kt = 1; kt <= T; ++kt) {
    if (kt < T) GLOAD(kt * 16);
#pragma unroll
    for (int kk = 0; kk < 16; ++kk) {
      float2 a = *(const float2*)&As[kk][tm * 2];
      float4 b = *(const float4*)&Bs[kk][tn * 4];
      acc[0][0] += a.x * b.x; acc[0][1] += a.x * b.y;
      acc[0][2] += a.x * b.z; acc[0][3] += a.x * b.w;
      acc[1][0] += a.y * b.x; acc[1][1] += a.y * b.y;
      acc[1][2] += a.y * b.z; acc[1][3] += a.y * b.w;
    }
    if (kt < T) {
      __syncthreads();
      DSW();
      __syncthreads();
    }
  }
#pragma unroll
  for (int mi = 0; mi < 2; ++mi) {
    int gm = m0 + tm * 2 + mi;
    if (gm >= M) continue;
    int gn = n0 + tn * 4;
    if (gn + 3 < N) {
      float4 o4 = make_float4(alpha * acc[mi][0], alpha * acc[mi][1],
                              alpha * acc[mi][2], alpha * acc[mi][3]);
      *(float4*)&C[(size_t)gm * N + gn] = o4;
    } else {
#pragma unroll
      for (int ni = 0; ni < 4; ++ni)
        if (gn + ni < N) C[(size_t)gm * N + gn + ni] = alpha * acc[mi][ni];
    }
  }
}

// ---- causal depthwise conv (k=4) + silu; handles direction reversal ----
__global__ void k_conv_silu(const float* __restrict__ xz, const float* __restrict__ cw,
                            const float* __restrict__ cb, float* __restrict__ xs, int l) {
  int gid = blockIdx.x * blockDim.x + threadIdx.x;
  if (gid >= 2 * 2 * NB * SL * DI) return;
  int d = gid % DI;
  int t = (gid / DI) % SL;
  int b = (gid / (DI * SL)) % NB;
  int dir = (gid / (DI * SL * NB)) % 2;
  int e = gid / (DI * SL * NB * 2);
  size_t pidx = (size_t)(e * NL + l) * 2 + dir;
  const float* cwp = cw + (pidx * DI + d) * DC;
  float acc = cb[pidx * DI + d];
#pragma unroll
  for (int k = 0; k < DC; ++k) {
    int ts = t - (DC - 1) + k;
    if (ts >= 0) {
      int torig = dir ? (SL - 1 - ts) : ts;
      acc += cwp[k] * xz[((size_t)(e * NB + b) * SL + torig) * XZW + d];
    }
  }
  xs[gid] = siluf(acc);
}

// ---- delta = softplus(dt @ dw^T + db) ----
__global__ void k_delta(const float* __restrict__ dbl, const float* __restrict__ dtw,
                        const float* __restrict__ dtb, float* __restrict__ delta, int l) {
  int gid = blockIdx.x * blockDim.x + threadIdx.x;
  if (gid >= 2 * 2 * NB * SL * DI) return;
  int d = gid % DI;
  int t = (gid / DI) % SL;
  int b = (gid / (DI * SL)) % NB;
  int dir = (gid / (DI * SL * NB)) % 2;
  int e = gid / (DI * SL * NB * 2);
  int z = e * 2 + dir;
  size_t pidx = (size_t)(e * NL + l) * 2 + dir;
  const float* row = dbl + ((size_t)(z * NB + b) * SL + t) * DBLW;
  const float* w = dtw + (pidx * DI + d) * DTR;
  float acc = dtb[pidx * DI + d];
#pragma unroll
  for (int r = 0; r < DTR; ++r) acc += row[r] * w[r];
  delta[gid] = softplusf(acc);
}

// ---- selective scan: 4-way t-segment parallel, intra-block carry fix-up ----
// Block = 4 waves; wave w = segment w (~50 steps) of 4 channels x 16 states.
// Pass 1: local recurrence from h=0, keep only h_end and A_prod (exact
// linear decomposition: h_seg_end = A_prod*h_in + h_end_local).
// Carry: LDS exchange + per-lane 3-FMA composition -> h_in per wave.
// Pass 2: rerun recurrence from h_in with y output (DPP n-reduce, z-gate).
// Grid 1536 blocks (6/CU, 24 waves/CU): TLP hides L2 latency.
__global__ __launch_bounds__(256) void k_scan(
    const float* __restrict__ xs, const float* __restrict__ delta,
    const float* __restrict__ dbl, const float* __restrict__ xz,
    const float* __restrict__ alog, const float* __restrict__ dpw,
    float* __restrict__ y0, float* __restrict__ y1, int l) {
  int bx = blockIdx.x;
  int g4 = bx % (DI / 4);
  int b = (bx / (DI / 4)) % NB;
  int dir = (bx / (DI / 4 * NB)) % 2;
  int e = bx / (DI / 4 * NB * 2);
  int tid = threadIdx.x;
  int w = tid >> 6;        // wave id = segment id
  int lane = tid & 63;
  int n = lane & 15;       // state index
  int chl = lane >> 4;     // 0..3
  int d = g4 * 4 + chl;
  size_t pidx = (size_t)(e * NL + l) * 2 + dir;
  float A = -expf(alog[(pidx * DI + d) * DSt + n]);
  float dpv = dpw[pidx * DI + d];
  int z = e * 2 + dir;
  size_t gdbase = ((size_t)(z * NB + b) * SL) * DI + d;
  size_t dblbase = ((size_t)(z * NB + b) * SL) * DBLW;
  size_t gzbase = ((size_t)(e * NB + b) * SL) * XZW + DI + d;
  float* yout = dir ? y1 : y0;
  size_t ybase = ((size_t)(e * NB + b) * SL) * DI + d;

  int t0 = w * SEG;
  int t1 = min(SL, t0 + SEG);

  // ---- pass 1: local h_end and A_prod (no y, no stores) ----
  float h = 0.f, ap = 1.f;
#pragma unroll 2
  for (int t = t0; t < t1; ++t) {
    float dv = delta[gdbase + (size_t)t * DI];
    float xv = xs[gdbase + (size_t)t * DI];
    float bm = dbl[dblbase + (size_t)t * DBLW + DTR + n];
    float a = __expf(dv * A);
    h = a * h + (dv * xv) * bm;
    ap *= a;
  }

  // ---- carry composition ----
  __shared__ float sh_h[4][64];
  __shared__ float sh_a[4][64];
  sh_h[w][lane] = h;
  sh_a[w][lane] = ap;
  __syncthreads();
  float hin = 0.f;
#pragma unroll
  for (int j = 0; j < 3; ++j)
    if (j < w) hin = sh_a[j][lane] * hin + sh_h[j][lane];

  // ---- pass 2: full recurrence from hin with output ----
  h = hin;
#pragma unroll 2
  for (int t = t0; t < t1; ++t) {
    float dv = delta[gdbase + (size_t)t * DI];
    float xv = xs[gdbase + (size_t)t * DI];
    float bm = dbl[dblbase + (size_t)t * DBLW + DTR + n];
    float cv = dbl[dblbase + (size_t)t * DBLW + DTR + DSt + n];
    float a = __expf(dv * A);
    h = a * h + (dv * xv) * bm;
    float pc = h * cv;
    pc = dpp_addf<0xB1>(pc);   // quad xor1
    pc = dpp_addf<0x4E>(pc);   // quad xor2
    pc = dpp_addf<0x114>(pc);  // row_shr:4
    pc = dpp_addf<0x118>(pc);  // row_shr:8
    if (n == 15) {
      int torig = dir ? (SL - 1 - t) : t;
      float zv = xz[gzbase + (size_t)torig * XZW];
      float yv = pc + xv * dpv;
      yout[ybase + (size_t)torig * DI] = yv * siluf(zv);
    }
  }
}

// ---- final: rmsnorm(h+res)*nfw, drop cls, token-major fT (e,b,196,192) ----
__global__ __launch_bounds__(DM) void k_final_norm(
    const float* __restrict__ h, const float* __restrict__ res,
    const float* __restrict__ nfw, float* __restrict__ fT) {
  int bx = blockIdx.x;
  int tk = bx % NT; int b = (bx / NT) % NB; int e = bx / (NT * NB);
  int c = threadIdx.x;
  __shared__ float wsum[3];
  size_t base = ((size_t)(e * NB + b) * SL + (tk + 1)) * DM;
  float r = h[base + c] + res[base + c];
  float tot = blk_sum3(r * r, wsum);
  float scale = rsqrtf(tot / (float)DM + 1e-5f);
  fT[((size_t)(e * NB + b) * NT + tk) * DM + c] = r * scale * nfw[e * DM + c];
}

// ---- depthwise 3x3 SAME over 14x14; in token-major, out channel-major ----
__global__ void k_dwconv(const float* __restrict__ qkvl, const float* __restrict__ qdw,
                         const float* __restrict__ kdw, const float* __restrict__ vdw,
                         float* __restrict__ qkvd) {
  int gid = blockIdx.x * blockDim.x + threadIdx.x;
  if (gid >= 3 * NB * DM * NT) return;
  int nn = gid % NT;
  int o = (gid / NT) % DM;
  int b = (gid / (NT * DM)) % NB;
  int zz = gid / (NT * DM * NB);
  const float* wsel = (zz == 0 ? qdw : (zz == 1 ? kdw : vdw)) + o * 9;
  int y = nn / HP, x = nn % HP;
  const float* in = qkvl + ((size_t)zz * NB + b) * NT * DM;
  float acc = 0.f;
#pragma unroll
  for (int ky = 0; ky < 3; ++ky) {
    int yy = y + ky - 1;
    if (yy < 0 || yy >= HP) continue;
#pragma unroll
    for (int kx = 0; kx < 3; ++kx) {
      int xx = x + kx - 1;
      if (xx < 0 || xx >= HP) continue;
      acc += in[(size_t)(yy * HP + xx) * DM + o] * wsel[ky * 3 + kx];
    }
  }
  qkvd[gid] = acc;
}

// ---- L2-normalize q,k rows over n=196 (in place) ----
__global__ __launch_bounds__(256) void k_l2norm(float* __restrict__ qkvd) {
  int bx = blockIdx.x;
  int C = bx % DM; int b = (bx / DM) % NB; int zz = bx / (DM * NB);
  int i = threadIdx.x;
  __shared__ float wsum[4];
  float* row = qkvd + ((size_t)zz * NB + b) * DM * NT + (size_t)C * NT;
  float v = (i < NT) ? row[i] : 0.f;
  float tot = blk_sum4(v * v, wsum);
  float sc = 1.f / fmaxf(sqrtf(tot), 1e-12f);
  if (i < NT) row[i] = v * sc;
}

// ---- S = temp*qn.kn^T, softmax over j (block=(b,h,i), 64 threads=j) ----
__global__ __launch_bounds__(64) void k_attn_sm(const float* __restrict__ qkvd,
                                                const float* __restrict__ temp,
                                                float* __restrict__ P) {
  int bx = blockIdx.x;
  int i = bx % 64; int hh = (bx / 64) % NH; int b = bx / (64 * NH);
  int j = threadIdx.x;
  __shared__ float qs[NT];
  const float* qrow = qkvd + ((size_t)0 * NB + b) * DM * NT + (size_t)(hh * 64 + i) * NT;
  for (int k = j; k < NT; k += 64) qs[k] = qrow[k];
  __syncthreads();
  const float* krow = qkvd + ((size_t)1 * NB + b) * DM * NT + (size_t)(hh * 64 + j) * NT;
  float acc = 0.f;
  for (int k = 0; k < NT; ++k) acc += qs[k] * krow[k];
  acc *= temp[hh];
  float m = acc;
  for (int off = 32; off; off >>= 1) m = fmaxf(m, __shfl_xor(m, off, 64));
  float ex = expf(acc - m);
  float s = ex;
  for (int off = 32; off; off >>= 1) s += __shfl_xor(s, off, 64);
  P[((size_t)(b * NH + hh) * 64 + i) * 64 + j] = ex / s;
}

// ---- out = P @ vh ----
__global__ __launch_bounds__(256) void k_av(const float* __restrict__ P,
                                            const float* __restrict__ qkvd,
                                            float* __restrict__ att) {
  int bx = blockIdx.x;
  int i = bx % 64; int hh = (bx / 64) % NH; int b = bx / (64 * NH);
  int nn = threadIdx.x;
  __shared__ float ps[64];
  if (nn < 64) ps[nn] = P[((size_t)(b * NH + hh) * 64 + i) * 64 + nn];
  __syncthreads();
  if (nn >= NT) return;
  const float* vbase = qkvd + ((size_t)2 * NB + b) * DM * NT + (size_t)(hh * 64) * NT + nn;
  float acc = 0.f;
  for (int j = 0; j < 64; ++j) acc += ps[j] * vbase[(size_t)j * NT];
  att[((size_t)b * DM + hh * 64 + i) * NT + nn] = acc;
}

// ---- final pointwise projection to d_out ----
__global__ __launch_bounds__(256) void k_out(const float* __restrict__ att,
                                             const float* __restrict__ pw,
                                             float* __restrict__ out) {
  int bx = blockIdx.x;
  int o = bx % DM; int b = bx / DM;
  int nn = threadIdx.x;
  if (nn >= NT) return;
  const float* abase = att + (size_t)b * DM * NT + nn;
  const float* w = pw + (size_t)o * DM;
  float acc = 0.f;
  for (int c = 0; c < DM; ++c) acc += abase[(size_t)c * NT] * w[c];
  out[((size_t)b * DM + o) * NT + nn] = acc;
}

extern "C" void kernel_launch(void* const* d_in, const int* in_sizes, int n_in,
                              void* d_out, int out_size, void* d_ws, size_t ws_size,
                              hipStream_t stream) {
  const float* x1      = (const float*)d_in[0];
  const float* x2      = (const float*)d_in[1];
  const float* patch_w = (const float*)d_in[2];
  const float* patch_b = (const float*)d_in[3];
  const float* cls_tok = (const float*)d_in[4];
  const float* pos_emb = (const float*)d_in[5];
  const float* norm_w  = (const float*)d_in[6];
  const float* in_w    = (const float*)d_in[7];
  const float* conv_w  = (const float*)d_in[8];
  const float* conv_b  = (const float*)d_in[9];
  const float* xp_w    = (const float*)d_in[10];
  const float* dt_w    = (const float*)d_in[11];
  const float* dt_b    = (const float*)d_in[12];
  const float* A_log   = (const float*)d_in[13];
  const float* Dp      = (const float*)d_in[14];
  const float* out_w   = (const float*)d_in[15];
  const float* normf_w = (const float*)d_in[16];
  const float* qw      = (const float*)d_in[17];
  const float* qdw     = (const float*)d_in[18];
  const float* kw      = (const float*)d_in[19];
  const float* kdw     = (const float*)d_in[20];
  const float* vw      = (const float*)d_in[21];
  const float* vdw     = (const float*)d_in[22];
  const float* pww     = (const float*)d_in[23];
  const float* temp    = (const float*)d_in[24];

  float* ws = (float*)d_ws;
  size_t o = 0;
  float* cosT = ws + o; o += (size_t)NT * DM;
  float* sinT = ws + o; o += (size_t)NT * DM;
  float* hB   = ws + o; o += 2ull * NB * SL * DM;
  float* resB = ws + o; o += 2ull * NB * SL * DM;
  float* hsB  = ws + o; o += 2ull * NB * SL * DM;
  float* xzB  = ws + o; o += 2ull * NB * SL * XZW;
  float* xsB  = ws + o; o += 4ull * NB * SL * DI;
  float* dblB = ws + o; o += 4ull * NB * SL * DBLW;
  float* delB = ws + o; o += 4ull * NB * SL * DI;   // aliased as im2col P before layers
  float* y0B  = ws + o; o += 2ull * NB * SL * DI;   // aliased as patch mm out before layers
  float* y1B  = ws + o; o += 2ull * NB * SL * DI;
  float* fTB  = ws + o; o += 2ull * NB * NT * DM;
  float* qkvL = ws + o; o += 3ull * NB * NT * DM;
  float* qkvD = ws + o; o += 3ull * NB * DM * NT;
  float* Pb   = ws + o; o += (size_t)NB * NH * 64 * 64;
  float* attB = ws + o; o += (size_t)NB * DM * NT;
  (void)ws_size; (void)in_sizes; (void)n_in; (void)out_size;

  const int M = NB * SL;  // 788 rows per encoder

  k_rope_init<<<(NT * DM + 255) / 256, 256, 0, stream>>>(cosT, sinT);

  // patch embed as im2col + GEMM + epilogue (delB/y0B reused as scratch here)
  float* Pm = delB;       // (2, 784, 768)
  float* Pout = y0B;      // (2, 784, 192)
  k_im2col<<<(2 * 784 * 768 + 255) / 256, 256, 0, stream>>>(x1, x2, Pm);
  {
    MM4 p{};
    for (int e = 0; e < 2; ++e) {
      p.A0[e] = Pm + (size_t)e * 784 * 768;
      p.A1[e] = nullptr;
      p.B[e]  = patch_w + (size_t)e * DM * 768;
      p.C[e]  = Pout + (size_t)e * 784 * DM;
    }
    dim3 g((DM + 63) / 64, (784 + 31) / 32, 2);
    k_mm32<<<g, 256, 0, stream>>>(p, 784, DM, 768, 1.f);
  }
  k_patch_fin<<<(2 * NB * SL * DM + 255) / 256, 256, 0, stream>>>(
      Pout, patch_b, cls_tok, pos_emb, hB, resB);

  for (int l = 0; l < NL; ++l) {
    k_rope_res_norm<<<2 * NB * SL, DM, 0, stream>>>(hB, resB, hsB, norm_w, cosT, sinT, l);

    // xz = hs @ in_w^T  (per encoder)
    {
      MM4 p{};
      for (int e = 0; e < 2; ++e) {
        p.A0[e] = hsB + (size_t)e * M * DM;
        p.A1[e] = nullptr;
        p.B[e]  = in_w + (size_t)(e * NL + l) * XZW * DM;
        p.C[e]  = xzB + (size_t)e * M * XZW;
      }
      dim3 g((XZW + 63) / 64, (M + 31) / 32, 2);
      k_mm32<<<g, 256, 0, stream>>>(p, M, XZW, DM, 1.f);
    }

    k_conv_silu<<<(2 * 2 * NB * SL * DI + 255) / 256, 256, 0, stream>>>(xzB, conv_w, conv_b, xsB, l);

    // dbl = xs @ xp_w^T (per e,dir)
    {
      MM4 p{};
      for (int z = 0; z < 4; ++z) {
        int e = z / 2, dir = z % 2;
        p.A0[z] = xsB + (size_t)z * M * DI;
        p.A1[z] = nullptr;
        p.B[z]  = xp_w + ((size_t)(e * NL + l) * 2 + dir) * DBLW * DI;
        p.C[z]  = dblB + (size_t)z * M * DBLW;
      }
      dim3 g((DBLW + 63) / 64, (M + 31) / 32, 4);
      k_mm32<<<g, 256, 0, stream>>>(p, M, DBLW, DI, 1.f);
    }

    k_delta<<<(2 * 2 * NB * SL * DI + 255) / 256, 256, 0, stream>>>(dblB, dt_w, dt_b, delB, l);

    k_scan<<<2 * 2 * NB * (DI / 4), 256, 0, stream>>>(xsB, delB, dblB, xzB, A_log, Dp, y0B, y1B, l);

    // h = 0.5*(y0+y1) @ out_w^T (per encoder)
    {
      MM4 p{};
      for (int e = 0; e < 2; ++e) {
        p.A0[e] = y0B + (size_t)e * M * DI;
        p.A1[e] = y1B + (size_t)e * M * DI;
        p.B[e]  = out_w + (size_t)(e * NL + l) * DM * DI;
        p.C[e]  = hB + (size_t)e * M * DM;
      }
      dim3 g((DM + 63) / 64, (M + 31) / 32, 2);
      k_mm32<<<g, 256, 0, stream>>>(p, M, DM, DI, 0.5f);
    }
  }

  k_final_norm<<<2 * NB * NT, DM, 0, stream>>>(hB, resB, normf_w, fTB);

  // q/k/v linear: q from f1 (e=0), k,v from f2 (e=1)
  {
    MM4 p{};
    const int Mq = NB * NT;  // 784
    p.A0[0] = fTB;                         p.A1[0] = nullptr; p.B[0] = qw; p.C[0] = qkvL;
    p.A0[1] = fTB + (size_t)NB * NT * DM;  p.A1[1] = nullptr; p.B[1] = kw; p.C[1] = qkvL + (size_t)Mq * DM;
    p.A0[2] = fTB + (size_t)NB * NT * DM;  p.A1[2] = nullptr; p.B[2] = vw; p.C[2] = qkvL + 2ull * Mq * DM;
    dim3 g((DM + 63) / 64, (Mq + 31) / 32, 3);
    k_mm32<<<g, 256, 0, stream>>>(p, Mq, DM, DM, 1.f);
  }

  k_dwconv<<<(3 * NB * DM * NT + 255) / 256, 256, 0, stream>>>(qkvL, qdw, kdw, vdw, qkvD);
  k_l2norm<<<2 * NB * DM, 256, 0, stream>>>(qkvD);
  k_attn_sm<<<NB * NH * 64, 64, 0, stream>>>(qkvD, temp, Pb);
  k_av<<<NB * NH * 64, 256, 0, stream>>>(Pb, qkvD, attB);
  k_out<<<NB * DM, 256, 0, stream>>>(attB, pww, (float*)d_out);
}

// Round 13
// 2852.996 us; speedup vs baseline: 1.2040x; 1.2040x over previous
//
#include <hip/hip_runtime.h>

#define DM 192      // D_MODEL
#define DI 384      // D_INNER
#define DSt 16      // D_STATE
#define DTR 12      // DT_RANK
#define DC 4        // D_CONV
#define NL 24       // DEPTH
#define HP 14
#define NH 3
#define NB 4        // BATCH
#define SL 197      // seq len (tokens + cls)
#define NT 196      // spatial tokens
#define XZW 768     // 2*D_INNER
#define DBLW 44     // DT_RANK + 2*D_STATE
#define NSEG 8      // scan t-segments per block (8 waves)
#define SEGL 25     // ceil(197/8)

static __device__ __forceinline__ float siluf(float x) { return x / (1.f + expf(-x)); }
static __device__ __forceinline__ float softplusf(float x) { return (x > 20.f) ? x : log1pf(expf(x)); }

// DPP-based add of a shifted copy (VALU pipe, no LDS crossbar).
template <int CTRL>
static __device__ __forceinline__ float dpp_addf(float x) {
  int y = __builtin_amdgcn_update_dpp(0, __float_as_int(x), CTRL, 0xF, 0xF, true);
  return x + __int_as_float(y);
}

// ---- block reduce helpers ----
static __device__ __forceinline__ float blk_sum3(float v, float* wsum) {
  for (int off = 32; off; off >>= 1) v += __shfl_xor(v, off, 64);
  int wid = threadIdx.x >> 6;
  if ((threadIdx.x & 63) == 0) wsum[wid] = v;
  __syncthreads();
  return wsum[0] + wsum[1] + wsum[2];
}
static __device__ __forceinline__ float blk_sum4(float v, float* wsum) {
  for (int off = 32; off; off >>= 1) v += __shfl_xor(v, off, 64);
  int wid = threadIdx.x >> 6;
  if ((threadIdx.x & 63) == 0) wsum[wid] = v;
  __syncthreads();
  return wsum[0] + wsum[1] + wsum[2] + wsum[3];
}

// ---- rope tables: cos/sin (196,192) ----
__global__ void k_rope_init(float* __restrict__ cosT, float* __restrict__ sinT) {
  int gid = blockIdx.x * blockDim.x + threadIdx.x;
  if (gid >= NT * DM) return;
  int c = gid % DM, tk = gid / DM;
  int py = tk / HP, px = tk % HP;
  int pos = (c < 96) ? py : px;
  int i = (c < 96) ? (c >> 1) : ((c - 96) >> 1);
  double fb = pow(10000.0, -((double)(2 * i)) / 96.0);
  double ang = (double)pos * fb;
  cosT[gid] = (float)cos(ang);
  sinT[gid] = (float)sin(ang);
}

// ---- im2col: P (2, 784, 768) patch matrix ----
__global__ void k_im2col(const float* __restrict__ x1, const float* __restrict__ x2,
                         float* __restrict__ P) {
  int gid = blockIdx.x * blockDim.x + threadIdx.x;
  if (gid >= 2 * 784 * 768) return;
  int col = gid % 768;
  int row = (gid / 768) % 784;
  int e = gid / (768 * 784);
  int b = row / NT, tk = row % NT;
  int c = col >> 8, r = (col >> 4) & 15, xx = col & 15;
  int py = tk / HP, px = tk % HP;
  const float* img = e ? x2 : x1;
  P[gid] = img[((size_t)(b * 3 + c) * 224 + (py * 16 + r)) * 224 + (px * 16 + xx)];
}

// ---- patch epilogue: h = mm_out + pb + pos (cls row special); res = 0 ----
__global__ void k_patch_fin(const float* __restrict__ pm, const float* __restrict__ pb,
                            const float* __restrict__ cls, const float* __restrict__ pos,
                            float* __restrict__ h, float* __restrict__ res) {
  int gid = blockIdx.x * blockDim.x + threadIdx.x;
  if (gid >= 2 * NB * SL * DM) return;
  int c = gid % DM;
  int t = (gid / DM) % SL;
  int b = (gid / (DM * SL)) % NB;
  int e = gid / (DM * SL * NB);
  float v;
  if (t == 0) v = cls[e * DM + c];
  else v = pm[((size_t)e * 784 + b * NT + (t - 1)) * DM + c] + pb[e * DM + c];
  h[gid] = v + pos[((size_t)e * SL + t) * DM + c];
  res[gid] = 0.f;
}

// ---- per layer: rope(h); res += ; hs = rmsnorm(res)*nw ----
__global__ __launch_bounds__(DM) void k_rope_res_norm(
    const float* __restrict__ h, float* __restrict__ res, float* __restrict__ hs,
    const float* __restrict__ nw, const float* __restrict__ cosT,
    const float* __restrict__ sinT, int l) {
  int bx = blockIdx.x;
  int t = bx % SL; int b = (bx / SL) % NB; int e = bx / (SL * NB);
  int c = threadIdx.x;
  __shared__ float sh[DM];
  __shared__ float wsum[3];
  size_t base = ((size_t)(e * NB + b) * SL + t) * DM;
  sh[c] = h[base + c];
  __syncthreads();
  float v = sh[c];
  if (t > 0) {
    int tk = t - 1;
    float co = cosT[tk * DM + c], si = sinT[tk * DM + c];
    float partner = sh[c ^ 1];
    float rot = (c & 1) ? partner : -partner;
    v = v * co + rot * si;
  }
  float r = res[base + c] + v;
  res[base + c] = r;
  float tot = blk_sum3(r * r, wsum);
  float scale = rsqrtf(tot / (float)DM + 1e-5f);
  hs[base + c] = r * scale * nw[(size_t)(e * NL + l) * DM + c];
}

// ---- register-blocked tiled GEMM: C = alpha*(A0[+A1]) @ B^T ----
// 32x64 tile, BK=16, 256 threads, 2x4 outputs/thread (float2 x float4).
struct MM4 {
  const float* A0[4];
  const float* A1[4];
  const float* B[4];
  float* C[4];
};
__global__ __launch_bounds__(256) void k_mm32(MM4 p, int M, int N, int K, float alpha) {
  const float* __restrict__ A0 = p.A0[blockIdx.z];
  const float* __restrict__ A1 = p.A1[blockIdx.z];
  const float* __restrict__ Bw = p.B[blockIdx.z];
  float* __restrict__ C = p.C[blockIdx.z];
  __shared__ __align__(16) float As[16][34];
  __shared__ __align__(16) float Bs[16][68];
  int tid = threadIdx.x;
  int m0 = blockIdx.y * 32, n0 = blockIdx.x * 64;
  int tm = tid >> 4, tn = tid & 15;        // compute roles: rows tm*2..+1, cols tn*4..+3
  int srow = tid >> 2, skq = tid & 3;      // B staging: 64 rows x 4 quads
  int srowA = (tid & 127) >> 2;            // A staging (tid<128): 32 rows x 4 quads
  bool doA = tid < 128;
  int gmA = min(m0 + srowA, M - 1);
  int gnB = min(n0 + srow, N - 1);
  bool hasA1 = (A1 != nullptr);
  float4 ra, rb, ra1;

  auto GLOAD = [&](int k0) {
    if (doA) {
      ra = *(const float4*)&A0[(size_t)gmA * K + k0 + skq * 4];
      if (hasA1) ra1 = *(const float4*)&A1[(size_t)gmA * K + k0 + skq * 4];
    }
    rb = *(const float4*)&Bw[(size_t)gnB * K + k0 + skq * 4];
  };
  auto DSW = [&]() {
    int kb = skq * 4;
    if (doA) {
      float av0 = ra.x, av1 = ra.y, av2 = ra.z, av3 = ra.w;
      if (hasA1) { av0 += ra1.x; av1 += ra1.y; av2 += ra1.z; av3 += ra1.w; }
      As[kb + 0][srowA] = av0;
      As[kb + 1][srowA] = av1;
      As[kb + 2][srowA] = av2;
      As[kb + 3][srowA] = av3;
    }
    Bs[kb + 0][srow] = rb.x;
    Bs[kb + 1][srow] = rb.y;
    Bs[kb + 2][srow] = rb.z;
    Bs[kb + 3][srow] = rb.w;
  };

  float acc[2][4] = {};
  int T = K >> 4;
  GLOAD(0);
  DSW();
  __syncthreads();
#pragma unroll 1
  for (int kt = 1; kt <= T; ++kt) {
    if (kt < T) GLOAD(kt * 16);
#pragma unroll
    for (int kk = 0; kk < 16; ++kk) {
      float2 a = *(const float2*)&As[kk][tm * 2];
      float4 b = *(const float4*)&Bs[kk][tn * 4];
      acc[0][0] += a.x * b.x; acc[0][1] += a.x * b.y;
      acc[0][2] += a.x * b.z; acc[0][3] += a.x * b.w;
      acc[1][0] += a.y * b.x; acc[1][1] += a.y * b.y;
      acc[1][2] += a.y * b.z; acc[1][3] += a.y * b.w;
    }
    if (kt < T) {
      __syncthreads();
      DSW();
      __syncthreads();
    }
  }
#pragma unroll
  for (int mi = 0; mi < 2; ++mi) {
    int gm = m0 + tm * 2 + mi;
    if (gm >= M) continue;
    int gn = n0 + tn * 4;
    if (gn + 3 < N) {
      float4 o4 = make_float4(alpha * acc[mi][0], alpha * acc[mi][1],
                              alpha * acc[mi][2], alpha * acc[mi][3]);
      *(float4*)&C[(size_t)gm * N + gn] = o4;
    } else {
#pragma unroll
      for (int ni = 0; ni < 4; ++ni)
        if (gn + ni < N) C[(size_t)gm * N + gn + ni] = alpha * acc[mi][ni];
    }
  }
}

// ---- causal depthwise conv (k=4) + silu; handles direction reversal ----
__global__ void k_conv_silu(const float* __restrict__ xz, const float* __restrict__ cw,
                            const float* __restrict__ cb, float* __restrict__ xs, int l) {
  int gid = blockIdx.x * blockDim.x + threadIdx.x;
  if (gid >= 2 * 2 * NB * SL * DI) return;
  int d = gid % DI;
  int t = (gid / DI) % SL;
  int b = (gid / (DI * SL)) % NB;
  int dir = (gid / (DI * SL * NB)) % 2;
  int e = gid / (DI * SL * NB * 2);
  size_t pidx = (size_t)(e * NL + l) * 2 + dir;
  const float* cwp = cw + (pidx * DI + d) * DC;
  float acc = cb[pidx * DI + d];
#pragma unroll
  for (int k = 0; k < DC; ++k) {
    int ts = t - (DC - 1) + k;
    if (ts >= 0) {
      int torig = dir ? (SL - 1 - ts) : ts;
      acc += cwp[k] * xz[((size_t)(e * NB + b) * SL + torig) * XZW + d];
    }
  }
  xs[gid] = siluf(acc);
}

// ---- delta = softplus(dt @ dw^T + db) ----
__global__ void k_delta(const float* __restrict__ dbl, const float* __restrict__ dtw,
                        const float* __restrict__ dtb, float* __restrict__ delta, int l) {
  int gid = blockIdx.x * blockDim.x + threadIdx.x;
  if (gid >= 2 * 2 * NB * SL * DI) return;
  int d = gid % DI;
  int t = (gid / DI) % SL;
  int b = (gid / (DI * SL)) % NB;
  int dir = (gid / (DI * SL * NB)) % 2;
  int e = gid / (DI * SL * NB * 2);
  int z = e * 2 + dir;
  size_t pidx = (size_t)(e * NL + l) * 2 + dir;
  const float* row = dbl + ((size_t)(z * NB + b) * SL + t) * DBLW;
  const float* w = dtw + (pidx * DI + d) * DTR;
  float acc = dtb[pidx * DI + d];
#pragma unroll
  for (int r = 0; r < DTR; ++r) acc += row[r] * w[r];
  delta[gid] = softplusf(acc);
}

// ---- selective scan: 8-way t-segment parallel, 16ch x 4-state-quad lanes ----
// Block = 512 threads = 8 waves = 8 t-segments (~25 steps). Wave lane =
// ch*4 + st4: each lane holds 4 states in registers (bm/cv/alog as aligned
// float4), 16 channels -> dv/xv loads cover full 64B lines, dbl shared by
// only DI/16=24 blocks. n-reduce = 4 in-lane FMAs + 2 quad-perm DPPs.
// Pass 1 computes (h_end, A_prod) per segment; LDS carry composition gives
// exact h_in; pass 2 reruns with output. Fixes R12's 6.7x over-fetch while
// keeping its 4x->8x t-parallelism.
__global__ __launch_bounds__(512) void k_scan(
    const float* __restrict__ xs, const float* __restrict__ delta,
    const float* __restrict__ dbl, const float* __restrict__ xz,
    const float* __restrict__ alog, const float* __restrict__ dpw,
    float* __restrict__ y0, float* __restrict__ y1, int l) {
  int bx = blockIdx.x;
  int dg = bx % (DI / 16);
  int b = (bx / (DI / 16)) % NB;
  int dir = (bx / (DI / 16 * NB)) % 2;
  int e = bx / (DI / 16 * NB * 2);
  int tid = threadIdx.x;
  int w = tid >> 6;        // wave id = segment id (0..7)
  int lane = tid & 63;
  int ch = lane >> 2;      // 0..15
  int st4 = lane & 3;      // state quad
  int d = dg * 16 + ch;
  size_t pidx = (size_t)(e * NL + l) * 2 + dir;
  float4 a4 = *(const float4*)&alog[((size_t)(pidx * DI + d)) * DSt + st4 * 4];
  float A0 = -expf(a4.x), A1 = -expf(a4.y), A2 = -expf(a4.z), A3 = -expf(a4.w);
  float dpv = dpw[pidx * DI + d];
  int z = e * 2 + dir;
  size_t gdbase = ((size_t)(z * NB + b) * SL) * DI + d;
  size_t dblbase = ((size_t)(z * NB + b) * SL) * DBLW;
  size_t gzbase = ((size_t)(e * NB + b) * SL) * XZW + DI + d;
  float* yout = dir ? y1 : y0;
  size_t ybase = ((size_t)(e * NB + b) * SL) * DI + d;

  int t0 = w * SEGL;
  int t1 = min(SL, t0 + SEGL);

  // ---- pass 1: local (h_end, A_prod), no output ----
  float h0 = 0.f, h1 = 0.f, h2 = 0.f, h3 = 0.f;
  float p0 = 1.f, p1 = 1.f, p2 = 1.f, p3 = 1.f;
#pragma unroll 1
  for (int t = t0; t < t1; ++t) {
    float dv = delta[gdbase + (size_t)t * DI];
    float xv = xs[gdbase + (size_t)t * DI];
    float4 bm = *(const float4*)&dbl[dblbase + (size_t)t * DBLW + DTR + st4 * 4];
    float dvxv = dv * xv;
    float e0 = __expf(dv * A0), e1 = __expf(dv * A1);
    float e2 = __expf(dv * A2), e3 = __expf(dv * A3);
    h0 = e0 * h0 + dvxv * bm.x; p0 *= e0;
    h1 = e1 * h1 + dvxv * bm.y; p1 *= e1;
    h2 = e2 * h2 + dvxv * bm.z; p2 *= e2;
    h3 = e3 * h3 + dvxv * bm.w; p3 *= e3;
  }

  // ---- carry composition (exact: h_seg_end = Aprod*h_in + h_local) ----
  __shared__ __align__(16) float4 sh_h[NSEG][64];
  __shared__ __align__(16) float4 sh_a[NSEG][64];
  sh_h[w][lane] = make_float4(h0, h1, h2, h3);
  sh_a[w][lane] = make_float4(p0, p1, p2, p3);
  __syncthreads();
  float i0 = 0.f, i1 = 0.f, i2 = 0.f, i3 = 0.f;
#pragma unroll
  for (int j = 0; j < NSEG - 1; ++j) {
    if (j < w) {
      float4 hh = sh_h[j][lane];
      float4 aa = sh_a[j][lane];
      i0 = aa.x * i0 + hh.x;
      i1 = aa.y * i1 + hh.y;
      i2 = aa.z * i2 + hh.z;
      i3 = aa.w * i3 + hh.w;
    }
  }

  // ---- pass 2: rerun from h_in with output ----
  h0 = i0; h1 = i1; h2 = i2; h3 = i3;
#pragma unroll 1
  for (int t = t0; t < t1; ++t) {
    float dv = delta[gdbase + (size_t)t * DI];
    float xv = xs[gdbase + (size_t)t * DI];
    float4 bm = *(const float4*)&dbl[dblbase + (size_t)t * DBLW + DTR + st4 * 4];
    float4 cv = *(const float4*)&dbl[dblbase + (size_t)t * DBLW + DTR + DSt + st4 * 4];
    float dvxv = dv * xv;
    float e0 = __expf(dv * A0), e1 = __expf(dv * A1);
    float e2 = __expf(dv * A2), e3 = __expf(dv * A3);
    h0 = e0 * h0 + dvxv * bm.x;
    h1 = e1 * h1 + dvxv * bm.y;
    h2 = e2 * h2 + dvxv * bm.z;
    h3 = e3 * h3 + dvxv * bm.w;
    float pc = h0 * cv.x + h1 * cv.y + h2 * cv.z + h3 * cv.w;
    pc = dpp_addf<0xB1>(pc);   // quad xor1
    pc = dpp_addf<0x4E>(pc);   // quad xor2
    if (st4 == 0) {
      int torig = dir ? (SL - 1 - t) : t;
      float zv = xz[gzbase + (size_t)torig * XZW];
      float yv = pc + xv * dpv;
      yout[ybase + (size_t)torig * DI] = yv * siluf(zv);
    }
  }
}

// ---- final: rmsnorm(h+res)*nfw, drop cls, token-major fT (e,b,196,192) ----
__global__ __launch_bounds__(DM) void k_final_norm(
    const float* __restrict__ h, const float* __restrict__ res,
    const float* __restrict__ nfw, float* __restrict__ fT) {
  int bx = blockIdx.x;
  int tk = bx % NT; int b = (bx / NT) % NB; int e = bx / (NT * NB);
  int c = threadIdx.x;
  __shared__ float wsum[3];
  size_t base = ((size_t)(e * NB + b) * SL + (tk + 1)) * DM;
  float r = h[base + c] + res[base + c];
  float tot = blk_sum3(r * r, wsum);
  float scale = rsqrtf(tot / (float)DM + 1e-5f);
  fT[((size_t)(e * NB + b) * NT + tk) * DM + c] = r * scale * nfw[e * DM + c];
}

// ---- depthwise 3x3 SAME over 14x14; in token-major, out channel-major ----
__global__ void k_dwconv(const float* __restrict__ qkvl, const float* __restrict__ qdw,
                         const float* __restrict__ kdw, const float* __restrict__ vdw,
                         float* __restrict__ qkvd) {
  int gid = blockIdx.x * blockDim.x + threadIdx.x;
  if (gid >= 3 * NB * DM * NT) return;
  int nn = gid % NT;
  int o = (gid / NT) % DM;
  int b = (gid / (NT * DM)) % NB;
  int zz = gid / (NT * DM * NB);
  const float* wsel = (zz == 0 ? qdw : (zz == 1 ? kdw : vdw)) + o * 9;
  int y = nn / HP, x = nn % HP;
  const float* in = qkvl + ((size_t)zz * NB + b) * NT * DM;
  float acc = 0.f;
#pragma unroll
  for (int ky = 0; ky < 3; ++ky) {
    int yy = y + ky - 1;
    if (yy < 0 || yy >= HP) continue;
#pragma unroll
    for (int kx = 0; kx < 3; ++kx) {
      int xx = x + kx - 1;
      if (xx < 0 || xx >= HP) continue;
      acc += in[(size_t)(yy * HP + xx) * DM + o] * wsel[ky * 3 + kx];
    }
  }
  qkvd[gid] = acc;
}

// ---- L2-normalize q,k rows over n=196 (in place) ----
__global__ __launch_bounds__(256) void k_l2norm(float* __restrict__ qkvd) {
  int bx = blockIdx.x;
  int C = bx % DM; int b = (bx / DM) % NB; int zz = bx / (DM * NB);
  int i = threadIdx.x;
  __shared__ float wsum[4];
  float* row = qkvd + ((size_t)zz * NB + b) * DM * NT + (size_t)C * NT;
  float v = (i < NT) ? row[i] : 0.f;
  float tot = blk_sum4(v * v, wsum);
  float sc = 1.f / fmaxf(sqrtf(tot), 1e-12f);
  if (i < NT) row[i] = v * sc;
}

// ---- S = temp*qn.kn^T, softmax over j (block=(b,h,i), 64 threads=j) ----
__global__ __launch_bounds__(64) void k_attn_sm(const float* __restrict__ qkvd,
                                                const float* __restrict__ temp,
                                                float* __restrict__ P) {
  int bx = blockIdx.x;
  int i = bx % 64; int hh = (bx / 64) % NH; int b = bx / (64 * NH);
  int j = threadIdx.x;
  __shared__ float qs[NT];
  const float* qrow = qkvd + ((size_t)0 * NB + b) * DM * NT + (size_t)(hh * 64 + i) * NT;
  for (int k = j; k < NT; k += 64) qs[k] = qrow[k];
  __syncthreads();
  const float* krow = qkvd + ((size_t)1 * NB + b) * DM * NT + (size_t)(hh * 64 + j) * NT;
  float acc = 0.f;
  for (int k = 0; k < NT; ++k) acc += qs[k] * krow[k];
  acc *= temp[hh];
  float m = acc;
  for (int off = 32; off; off >>= 1) m = fmaxf(m, __shfl_xor(m, off, 64));
  float ex = expf(acc - m);
  float s = ex;
  for (int off = 32; off; off >>= 1) s += __shfl_xor(s, off, 64);
  P[((size_t)(b * NH + hh) * 64 + i) * 64 + j] = ex / s;
}

// ---- out = P @ vh ----
__global__ __launch_bounds__(256) void k_av(const float* __restrict__ P,
                                            const float* __restrict__ qkvd,
                                            float* __restrict__ att) {
  int bx = blockIdx.x;
  int i = bx % 64; int hh = (bx / 64) % NH; int b = bx / (64 * NH);
  int nn = threadIdx.x;
  __shared__ float ps[64];
  if (nn < 64) ps[nn] = P[((size_t)(b * NH + hh) * 64 + i) * 64 + nn];
  __syncthreads();
  if (nn >= NT) return;
  const float* vbase = qkvd + ((size_t)2 * NB + b) * DM * NT + (size_t)(hh * 64) * NT + nn;
  float acc = 0.f;
  for (int j = 0; j < 64; ++j) acc += ps[j] * vbase[(size_t)j * NT];
  att[((size_t)b * DM + hh * 64 + i) * NT + nn] = acc;
}

// ---- final pointwise projection to d_out ----
__global__ __launch_bounds__(256) void k_out(const float* __restrict__ att,
                                             const float* __restrict__ pw,
                                             float* __restrict__ out) {
  int bx = blockIdx.x;
  int o = bx % DM; int b = bx / DM;
  int nn = threadIdx.x;
  if (nn >= NT) return;
  const float* abase = att + (size_t)b * DM * NT + nn;
  const float* w = pw + (size_t)o * DM;
  float acc = 0.f;
  for (int c = 0; c < DM; ++c) acc += abase[(size_t)c * NT] * w[c];
  out[((size_t)b * DM + o) * NT + nn] = acc;
}

extern "C" void kernel_launch(void* const* d_in, const int* in_sizes, int n_in,
                              void* d_out, int out_size, void* d_ws, size_t ws_size,
                              hipStream_t stream) {
  const float* x1      = (const float*)d_in[0];
  const float* x2      = (const float*)d_in[1];
  const float* patch_w = (const float*)d_in[2];
  const float* patch_b = (const float*)d_in[3];
  const float* cls_tok = (const float*)d_in[4];
  const float* pos_emb = (const float*)d_in[5];
  const float* norm_w  = (const float*)d_in[6];
  const float* in_w    = (const float*)d_in[7];
  const float* conv_w  = (const float*)d_in[8];
  const float* conv_b  = (const float*)d_in[9];
  const float* xp_w    = (const float*)d_in[10];
  const float* dt_w    = (const float*)d_in[11];
  const float* dt_b    = (const float*)d_in[12];
  const float* A_log   = (const float*)d_in[13];
  const float* Dp      = (const float*)d_in[14];
  const float* out_w   = (const float*)d_in[15];
  const float* normf_w = (const float*)d_in[16];
  const float* qw      = (const float*)d_in[17];
  const float* qdw     = (const float*)d_in[18];
  const float* kw      = (const float*)d_in[19];
  const float* kdw     = (const float*)d_in[20];
  const float* vw      = (const float*)d_in[21];
  const float* vdw     = (const float*)d_in[22];
  const float* pww     = (const float*)d_in[23];
  const float* temp    = (const float*)d_in[24];

  float* ws = (float*)d_ws;
  size_t o = 0;
  float* cosT = ws + o; o += (size_t)NT * DM;
  float* sinT = ws + o; o += (size_t)NT * DM;
  float* hB   = ws + o; o += 2ull * NB * SL * DM;
  float* resB = ws + o; o += 2ull * NB * SL * DM;
  float* hsB  = ws + o; o += 2ull * NB * SL * DM;
  float* xzB  = ws + o; o += 2ull * NB * SL * XZW;
  float* xsB  = ws + o; o += 4ull * NB * SL * DI;
  float* dblB = ws + o; o += 4ull * NB * SL * DBLW;
  float* delB = ws + o; o += 4ull * NB * SL * DI;   // aliased as im2col P before layers
  float* y0B  = ws + o; o += 2ull * NB * SL * DI;   // aliased as patch mm out before layers
  float* y1B  = ws + o; o += 2ull * NB * SL * DI;
  float* fTB  = ws + o; o += 2ull * NB * NT * DM;
  float* qkvL = ws + o; o += 3ull * NB * NT * DM;
  float* qkvD = ws + o; o += 3ull * NB * DM * NT;
  float* Pb   = ws + o; o += (size_t)NB * NH * 64 * 64;
  float* attB = ws + o; o += (size_t)NB * DM * NT;
  (void)ws_size; (void)in_sizes; (void)n_in; (void)out_size;

  const int M = NB * SL;  // 788 rows per encoder

  k_rope_init<<<(NT * DM + 255) / 256, 256, 0, stream>>>(cosT, sinT);

  // patch embed as im2col + GEMM + epilogue (delB/y0B reused as scratch here)
  float* Pm = delB;       // (2, 784, 768)
  float* Pout = y0B;      // (2, 784, 192)
  k_im2col<<<(2 * 784 * 768 + 255) / 256, 256, 0, stream>>>(x1, x2, Pm);
  {
    MM4 p{};
    for (int e = 0; e < 2; ++e) {
      p.A0[e] = Pm + (size_t)e * 784 * 768;
      p.A1[e] = nullptr;
      p.B[e]  = patch_w + (size_t)e * DM * 768;
      p.C[e]  = Pout + (size_t)e * 784 * DM;
    }
    dim3 g((DM + 63) / 64, (784 + 31) / 32, 2);
    k_mm32<<<g, 256, 0, stream>>>(p, 784, DM, 768, 1.f);
  }
  k_patch_fin<<<(2 * NB * SL * DM + 255) / 256, 256, 0, stream>>>(
      Pout, patch_b, cls_tok, pos_emb, hB, resB);

  for (int l = 0; l < NL; ++l) {
    k_rope_res_norm<<<2 * NB * SL, DM, 0, stream>>>(hB, resB, hsB, norm_w, cosT, sinT, l);

    // xz = hs @ in_w^T  (per encoder)
    {
      MM4 p{};
      for (int e = 0; e < 2; ++e) {
        p.A0[e] = hsB + (size_t)e * M * DM;
        p.A1[e] = nullptr;
        p.B[e]  = in_w + (size_t)(e * NL + l) * XZW * DM;
        p.C[e]  = xzB + (size_t)e * M * XZW;
      }
      dim3 g((XZW + 63) / 64, (M + 31) / 32, 2);
      k_mm32<<<g, 256, 0, stream>>>(p, M, XZW, DM, 1.f);
    }

    k_conv_silu<<<(2 * 2 * NB * SL * DI + 255) / 256, 256, 0, stream>>>(xzB, conv_w, conv_b, xsB, l);

    // dbl = xs @ xp_w^T (per e,dir)
    {
      MM4 p{};
      for (int z = 0; z < 4; ++z) {
        int e = z / 2, dir = z % 2;
        p.A0[z] = xsB + (size_t)z * M * DI;
        p.A1[z] = nullptr;
        p.B[z]  = xp_w + ((size_t)(e * NL + l) * 2 + dir) * DBLW * DI;
        p.C[z]  = dblB + (size_t)z * M * DBLW;
      }
      dim3 g((DBLW + 63) / 64, (M + 31) / 32, 4);
      k_mm32<<<g, 256, 0, stream>>>(p, M, DBLW, DI, 1.f);
    }

    k_delta<<<(2 * 2 * NB * SL * DI + 255) / 256, 256, 0, stream>>>(dblB, dt_w, dt_b, delB, l);

    k_scan<<<2 * 2 * NB * (DI / 16), 512, 0, stream>>>(xsB, delB, dblB, xzB, A_log, Dp, y0B, y1B, l);

    // h = 0.5*(y0+y1) @ out_w^T (per encoder)
    {
      MM4 p{};
      for (int e = 0; e < 2; ++e) {
        p.A0[e] = y0B + (size_t)e * M * DI;
        p.A1[e] = y1B + (size_t)e * M * DI;
        p.B[e]  = out_w + (size_t)(e * NL + l) * DM * DI;
        p.C[e]  = hB + (size_t)e * M * DM;
      }
      dim3 g((DM + 63) / 64, (M + 31) / 32, 2);
      k_mm32<<<g, 256, 0, stream>>>(p, M, DM, DI, 0.5f);
    }
  }

  k_final_norm<<<2 * NB * NT, DM, 0, stream>>>(hB, resB, normf_w, fTB);

  // q/k/v linear: q from f1 (e=0), k,v from f2 (e=1)
  {
    MM4 p{};
    const int Mq = NB * NT;  // 784
    p.A0[0] = fTB;                         p.A1[0] = nullptr; p.B[0] = qw; p.C[0] = qkvL;
    p.A0[1] = fTB + (size_t)NB * NT * DM;  p.A1[1] = nullptr; p.B[1] = kw; p.C[1] = qkvL + (size_t)Mq * DM;
    p.A0[2] = fTB + (size_t)NB * NT * DM;  p.A1[2] = nullptr; p.B[2] = vw; p.C[2] = qkvL + 2ull * Mq * DM;
    dim3 g((DM + 63) / 64, (Mq + 31) / 32, 3);
    k_mm32<<<g, 256, 0, stream>>>(p, Mq, DM, DM, 1.f);
  }

  k_dwconv<<<(3 * NB * DM * NT + 255) / 256, 256, 0, stream>>>(qkvL, qdw, kdw, vdw, qkvD);
  k_l2norm<<<2 * NB * DM, 256, 0, stream>>>(qkvD);
  k_attn_sm<<<NB * NH * 64, 64, 0, stream>>>(qkvD, temp, Pb);
  k_av<<<NB * NH * 64, 256, 0, stream>>>(Pb, qkvD, attB);
  k_out<<<NB * DM, 256, 0, stream>>>(attB, pww, (float*)d_out);
}